// Round 11
// baseline (558.299 us; speedup 1.0000x reference)
//
#include <hip/hip_runtime.h>
#include <hip/hip_bf16.h>
#include <cstddef>

#define B_   256
#define P_   196
#define DE_  2048
#define DD_  512
#define DA_  512
#define M_   (B_*P_)   // 50176

#define KT   32
#define NKT  (DE_/KT)  // 64

typedef __attribute__((ext_vector_type(4))) float f32x4;
typedef __attribute__((ext_vector_type(8))) short s16x8;

static __device__ __forceinline__ short f2bf(float x) {
    __hip_bfloat16 h = __float2bfloat16(x);
    return *reinterpret_cast<short*>(&h);
}

// ---------------------------------------------------------------------------
// Kernel 0: pack W_enc [K][N] fp32 -> bf16 per-fragment layout (proven r5+):
//   unit u = (kt*32 + gf)*64 + lane (16 B); lane l, j ->
//   W[kt*32 + (l>>4)*8 + j][gf*16 + (l&15)]
// ---------------------------------------------------------------------------
__global__ __launch_bounds__(256) void pack_wenc(
        const float* __restrict__ W, __hip_bfloat16* __restrict__ out) {
    __shared__ float lds[KT][DA_];          // 64 KB
    const int kt = blockIdx.x;
    const int t  = threadIdx.x;
#pragma unroll
    for (int i = 0; i < 64; ++i) {
        int e = i * 256 + t;
        int k = e >> 9, n = e & 511;
        lds[k][n] = W[(size_t)(kt * KT + k) * DA_ + n];
    }
    __syncthreads();
    short* o = reinterpret_cast<short*>(out) + (size_t)kt * (32 * 64 * 8);
#pragma unroll
    for (int i = 0; i < 8; ++i) {
        int idx  = i * 256 + t;
        int gf   = idx >> 6;
        int lane = idx & 63;
        int g = lane >> 4, c = lane & 15;
        s16x8 w;
#pragma unroll
        for (int j = 0; j < 8; ++j)
            w[j] = f2bf(lds[g * 8 + j][gf * 16 + c]);
        *reinterpret_cast<s16x8*>(o + (size_t)idx * 8) = w;
    }
}

// ---------------------------------------------------------------------------
// Kernel 1: att2p[b][a] = dh[b,:] @ W_dec[:,a] + b_dec[a] + b_enc[a]
// ---------------------------------------------------------------------------
__global__ __launch_bounds__(512) void att2_kernel(
        const float* __restrict__ dh, const float* __restrict__ W_dec,
        const float* __restrict__ b_dec, const float* __restrict__ b_enc,
        float* __restrict__ att2p) {
    __shared__ float s_dh[DD_];
    const int b = blockIdx.x;
    const int a = threadIdx.x;
    s_dh[a] = dh[(size_t)b * DD_ + a];
    __syncthreads();
    float acc = 0.f;
#pragma unroll 8
    for (int k = 0; k < DD_; ++k)
        acc += s_dh[k] * W_dec[(size_t)k * DA_ + a];
    att2p[(size_t)b * DA_ + a] = acc + b_dec[a] + b_enc[a];
}

// ---------------------------------------------------------------------------
// Kernel 2: GEMM 50176x512x2048, 1-WAVE blocks (64 thr), tile 64x64/wave.
// Zero barriers, zero LDS, zero inline asm. A: HBM/L2 -> regs (fp32, dbuf,
// 2-step distance) -> cvt bf16. B: L2 -> regs (prepacked frags, dbuf, 2-step).
// acc[4][4]=64 AGPR. 6272 independent waves; col-groups of an M-tile share
// an XCD (bid%8 == mtile%8). Partials to att_part[cg][M], summed in softmax.
// ---------------------------------------------------------------------------
__global__ __launch_bounds__(64, 2) void gemm_att(
        const float* __restrict__ enc, const __hip_bfloat16* __restrict__ Bp,
        const float* __restrict__ att2p, const float* __restrict__ Wfull,
        float* __restrict__ att_part) {
    const int lane = threadIdx.x;      // 0..63
    const int g    = lane >> 4;        // k-group 0..3
    const int c    = lane & 15;

    // bid = (mt/8)*64 + cg*8 + (mt%8)  ->  bid%8 == mt%8 (same XCD for all cg)
    const int bid = blockIdx.x;
    const int mt_ = (bid >> 6) * 8 + (bid & 7);   // 0..783
    const int cg  = (bid >> 3) & 7;               // col-group 0..7
    const int block_row = mt_ * 64;

    // A: frag mt2 = rows block_row+mt2*16+c, k = t*32 + g*8 .. +8
    const float* aptr = enc + (size_t)(block_row + c) * DE_ + g * 8;
    // B: frag (t, n) at unit ((t*32 + cg*4 + n)*64 + lane)
    const s16x8* bp = reinterpret_cast<const s16x8*>(Bp) + (size_t)(cg * 4) * 64 + lane;

    f32x4 acc[4][4] = {};
    f32x4 paX[4][2], paY[4][2];
    s16x8 bfX[4], bfY[4];

#define LOAD_A(dst, T) do {                                              \
        const int tt_ = (T) > 63 ? 63 : (T);                             \
        _Pragma("unroll")                                                \
        for (int m_ = 0; m_ < 4; ++m_) {                                 \
            const float* p_ = aptr + (size_t)m_ * (16 * DE_) + tt_ * KT; \
            dst[m_][0] = *reinterpret_cast<const f32x4*>(p_);            \
            dst[m_][1] = *reinterpret_cast<const f32x4*>(p_ + 4);        \
        }                                                                \
    } while (0)

#define LOAD_B(dst, T) do {                                              \
        const int tt_ = (T) > 63 ? 63 : (T);                             \
        _Pragma("unroll")                                                \
        for (int n_ = 0; n_ < 4; ++n_)                                   \
            dst[n_] = bp[((size_t)tt_ * 32 + n_) * 64];                  \
    } while (0)

#define STEP(pa, bfr) do {                                               \
        s16x8 af[4];                                                     \
        _Pragma("unroll")                                                \
        for (int m_ = 0; m_ < 4; ++m_) {                                 \
            s16x8 w_;                                                    \
            w_[0]=f2bf(pa[m_][0].x); w_[1]=f2bf(pa[m_][0].y);            \
            w_[2]=f2bf(pa[m_][0].z); w_[3]=f2bf(pa[m_][0].w);            \
            w_[4]=f2bf(pa[m_][1].x); w_[5]=f2bf(pa[m_][1].y);            \
            w_[6]=f2bf(pa[m_][1].z); w_[7]=f2bf(pa[m_][1].w);            \
            af[m_] = w_;                                                 \
        }                                                                \
        __builtin_amdgcn_s_setprio(1);                                   \
        _Pragma("unroll")                                                \
        for (int n_ = 0; n_ < 4; ++n_)                                   \
            _Pragma("unroll")                                            \
            for (int m_ = 0; m_ < 4; ++m_)                               \
                acc[m_][n_] = __builtin_amdgcn_mfma_f32_16x16x32_bf16(   \
                                  af[m_], bfr[n_], acc[m_][n_], 0, 0, 0);\
        __builtin_amdgcn_s_setprio(0);                                   \
    } while (0)

    // ---- prologue: steps 0 and 1 in flight ----
    LOAD_A(paX, 0);
    LOAD_B(bfX, 0);
    LOAD_A(paY, 1);
    LOAD_B(bfY, 1);

#pragma clang loop unroll(disable)
    for (int t = 0; t < NKT; t += 2) {
        STEP(paX, bfX);              // waits step-t loads (issued 2 steps ago)
        LOAD_A(paX, t + 2);          // refill X set
        LOAD_B(bfX, t + 2);
        STEP(paY, bfY);
        LOAD_A(paY, t + 3);
        LOAD_B(bfY, t + 3);
    }

    // ---- fused epilogue: partial relu-dot over this wave's 64 cols ----
    const int b0    = block_row / P_;
    const int b1    = min(b0 + 1, B_ - 1);
    const int split = (b0 + 1) * P_;
    float wf[4], a20[4], a21[4];
#pragma unroll
    for (int n = 0; n < 4; ++n) {
        const int col = cg * 64 + n * 16 + c;
        wf[n]  = Wfull[col];
        a20[n] = att2p[(size_t)b0 * DA_ + col];
        a21[n] = att2p[(size_t)b1 * DA_ + col];
    }
    float* dst = att_part + (size_t)cg * M_ + block_row;
#pragma unroll
    for (int mt = 0; mt < 4; ++mt) {
#pragma unroll
        for (int q = 0; q < 4; ++q) {
            const int row_local = mt * 16 + g * 4 + q;
            const bool hiB = (block_row + row_local >= split);
            float s = 0.f;
#pragma unroll
            for (int n = 0; n < 4; ++n) {
                float a2 = hiB ? a21[n] : a20[n];
                float v  = acc[mt][n][q] + a2;
                v = fmaxf(v, 0.f);
                s += v * wf[n];
            }
#pragma unroll
            for (int off = 1; off < 16; off <<= 1)
                s += __shfl_xor(s, off, 64);
            if (c == 0) dst[row_local] = s;
        }
    }
#undef LOAD_A
#undef LOAD_B
#undef STEP
}

// ---------------------------------------------------------------------------
// Kernel 3: softmax over P per batch -> alpha (sums 8 col-group partials)
// ---------------------------------------------------------------------------
__global__ __launch_bounds__(256) void softmax_kernel(
        const float* __restrict__ att_part, float* __restrict__ alpha) {
    const int b = blockIdx.x;
    const int t = threadIdx.x;
    __shared__ float sred[4];
    float v = -1e30f;
    if (t < P_) {
        const size_t R = (size_t)b * P_ + t;
        v = 0.f;
#pragma unroll
        for (int cgi = 0; cgi < 8; ++cgi)
            v += att_part[(size_t)cgi * M_ + R];
    }
    float m = v;
#pragma unroll
    for (int off = 1; off < 64; off <<= 1) m = fmaxf(m, __shfl_xor(m, off, 64));
    if ((t & 63) == 0) sred[t >> 6] = m;
    __syncthreads();
    const float mall = fmaxf(fmaxf(sred[0], sred[1]), fmaxf(sred[2], sred[3]));
    __syncthreads();
    float e = (t < P_) ? expf(v - mall) : 0.f;
    float s = e;
#pragma unroll
    for (int off = 1; off < 64; off <<= 1) s += __shfl_xor(s, off, 64);
    if ((t & 63) == 0) sred[t >> 6] = s;
    __syncthreads();
    const float stot = sred[0] + sred[1] + sred[2] + sred[3];
    if (t < P_) alpha[(size_t)b * P_ + t] = e / stot;
}

// ---------------------------------------------------------------------------
// Kernel 4: context[b][e] = sum_p alpha[b][p] * enc[b][p][e]
// ---------------------------------------------------------------------------
__global__ __launch_bounds__(256) void context_kernel(
        const float* __restrict__ enc, const float* __restrict__ alpha,
        float* __restrict__ ctx) {
    const int b = blockIdx.x;
    const int e = blockIdx.y * 1024 + threadIdx.x * 4;
    __shared__ float s_alpha[P_];
    if (threadIdx.x < P_) s_alpha[threadIdx.x] = alpha[(size_t)b * P_ + threadIdx.x];
    __syncthreads();
    f32x4 acc = {0.f, 0.f, 0.f, 0.f};
    const float* base = enc + (size_t)b * P_ * DE_ + e;
#pragma unroll 4
    for (int p = 0; p < P_; ++p) {
        f32x4 v = *reinterpret_cast<const f32x4*>(base + (size_t)p * DE_);
        acc += s_alpha[p] * v;
    }
    *reinterpret_cast<f32x4*>(ctx + (size_t)b * DE_ + e) = acc;
}

// ---------------------------------------------------------------------------
extern "C" void kernel_launch(void* const* d_in, const int* in_sizes, int n_in,
                              void* d_out, int out_size, void* d_ws, size_t ws_size,
                              hipStream_t stream) {
    const float* enc    = (const float*)d_in[0];
    const float* dh     = (const float*)d_in[1];
    const float* W_enc  = (const float*)d_in[2];
    const float* b_enc  = (const float*)d_in[3];
    const float* W_dec  = (const float*)d_in[4];
    const float* b_dec  = (const float*)d_in[5];
    const float* W_full = (const float*)d_in[6];

    float* out       = (float*)d_out;
    float* ctx_out   = out;                       // [B,DE]
    float* alpha_out = out + (size_t)B_ * DE_;    // [B,P]

    char* ws = (char*)d_ws;
    __hip_bfloat16* Bp  = (__hip_bfloat16*)ws;                        // 2 MB
    float* att2p    = (float*)(ws + 2u * 1024 * 1024);                // 512 KB
    float* att_part = (float*)(ws + 2u * 1024 * 1024 + 512u * 1024);  // 8 x 200 KB

    pack_wenc     <<<NKT,            256, 0, stream>>>(W_enc, Bp);
    att2_kernel   <<<B_,             512, 0, stream>>>(dh, W_dec, b_dec, b_enc, att2p);
    gemm_att      <<<(M_ / 64) * 8,  64,  0, stream>>>(enc, Bp, att2p, W_full, att_part);
    softmax_kernel<<<B_,             256, 0, stream>>>(att_part, alpha_out);
    context_kernel<<<dim3(B_, 2),    256, 0, stream>>>(enc, alpha_out, ctx_out);
}